// Round 1
// baseline (9994.670 us; speedup 1.0000x reference)
//
#include <hip/hip_runtime.h>
#include <cstdint>

static constexpr int BB = 2;
static constexpr int NN = 16384;
static constexpr int SS = 4096;

// ---------------------------------------------------------------------------
// FPS: one block per batch. 1024 threads, 16 points/thread in registers.
// Bit-exact distance math (no FMA contraction) to match the numpy reference,
// argmax with first-index tie-break.
// ---------------------------------------------------------------------------
__global__ __launch_bounds__(1024) void fps_kernel(
    const float* __restrict__ xyz, int* __restrict__ fps_idx,
    float* __restrict__ new_xyz)
{
  const int b = blockIdx.x;
  const float* X = xyz + (size_t)b * NN * 3;
  const int t = threadIdx.x;
  constexpr int PPT = NN / 1024;  // 16

  float px[PPT], py[PPT], pz[PPT], dist[PPT];
#pragma unroll
  for (int i = 0; i < PPT; ++i) {
    int p = t + i * 1024;
    px[i] = X[p * 3 + 0];
    py[i] = X[p * 3 + 1];
    pz[i] = X[p * 3 + 2];
    dist[i] = 1e10f;
  }

  __shared__ float s_lx, s_ly, s_lz;
  __shared__ float s_wval[16];
  __shared__ int   s_widx[16];

  if (t == 0) {
    s_lx = X[0]; s_ly = X[1]; s_lz = X[2];
    fps_idx[(size_t)b * SS] = 0;
    new_xyz[((size_t)b * SS) * 3 + 0] = X[0];
    new_xyz[((size_t)b * SS) * 3 + 1] = X[1];
    new_xyz[((size_t)b * SS) * 3 + 2] = X[2];
  }
  __syncthreads();

  const int lane = t & 63;
  const int wid = t >> 6;

  for (int it = 1; it < SS; ++it) {
    const float lx = s_lx, ly = s_ly, lz = s_lz;
    float bval = -1.f;
    int bidx = 0;
#pragma unroll
    for (int i = 0; i < PPT; ++i) {
      float dx = __fsub_rn(px[i], lx);
      float dy = __fsub_rn(py[i], ly);
      float dz = __fsub_rn(pz[i], lz);
      float d = __fadd_rn(__fadd_rn(__fmul_rn(dx, dx), __fmul_rn(dy, dy)),
                          __fmul_rn(dz, dz));
      float nd = fminf(dist[i], d);
      dist[i] = nd;
      if (nd > bval) { bval = nd; bidx = t + i * 1024; }  // ascending i -> keeps lowest idx on ties
    }
    // wave-level argmax reduce, tie -> smaller index
#pragma unroll
    for (int off = 32; off >= 1; off >>= 1) {
      float ov = __shfl_xor(bval, off);
      int   oi = __shfl_xor(bidx, off);
      if (ov > bval || (ov == bval && oi < bidx)) { bval = ov; bidx = oi; }
    }
    if (lane == 0) { s_wval[wid] = bval; s_widx[wid] = bidx; }
    __syncthreads();
    // every wave redundantly reduces the 16 wave-partials (avoids a broadcast barrier)
    float rv = s_wval[lane & 15];
    int   ri = s_widx[lane & 15];
#pragma unroll
    for (int off = 8; off >= 1; off >>= 1) {
      float ov = __shfl_xor(rv, off);
      int   oi = __shfl_xor(ri, off);
      if (ov > rv || (ov == rv && oi < ri)) { rv = ov; ri = oi; }
    }
    const int sel = ri;  // identical in all lanes/waves
    if (t == (sel & 1023)) {   // owner thread publishes xyz from its registers
      const int isel = sel >> 10;
#pragma unroll
      for (int i = 0; i < PPT; ++i) {
        if (i == isel) {
          s_lx = px[i]; s_ly = py[i]; s_lz = pz[i];
          fps_idx[(size_t)b * SS + it] = sel;
          new_xyz[((size_t)b * SS + it) * 3 + 0] = px[i];
          new_xyz[((size_t)b * SS + it) * 3 + 1] = py[i];
          new_xyz[((size_t)b * SS + it) * 3 + 2] = pz[i];
        }
      }
    }
    __syncthreads();
  }
}

// ---------------------------------------------------------------------------
// Ball query: one 64-lane wave per query point. Emits the first NS in-radius
// point indices in ascending order (matches reference top_k(-keys) trick),
// pads with the first hit.
// ---------------------------------------------------------------------------
template <int NS>
__global__ __launch_bounds__(256) void ballq_kernel(
    const float* __restrict__ xyz, const float* __restrict__ new_xyz,
    int* __restrict__ out, float r2)
{
  const int q = blockIdx.x * 4 + (threadIdx.x >> 6);
  const int lane = threadIdx.x & 63;
  const int b = q >> 12;  // q / SS
  const float* X = xyz + (size_t)b * NN * 3;
  const float cx = new_xyz[q * 3 + 0];
  const float cy = new_xyz[q * 3 + 1];
  const float cz = new_xyz[q * 3 + 2];
  int* o = out + (size_t)q * NS;
  int base = 0;
  int firstIdx = 0x7fffffff;
  for (int c0 = 0; c0 < NN; c0 += 64) {
    const int p = c0 + lane;
    float dx = __fsub_rn(cx, X[p * 3 + 0]);
    float dy = __fsub_rn(cy, X[p * 3 + 1]);
    float dz = __fsub_rn(cz, X[p * 3 + 2]);
    float d2 = __fadd_rn(__fadd_rn(__fmul_rn(dx, dx), __fmul_rn(dy, dy)),
                         __fmul_rn(dz, dz));
    const bool inb = d2 < r2;
    const unsigned long long m = __ballot(inb);
    if (inb) {
      int rank = base + (int)__popcll(m & ((1ull << lane) - 1ull));
      if (rank < NS) {
        o[rank] = p;
        if (rank == 0) firstIdx = p;
      }
    }
    base += (int)__popcll(m);
    if (base >= NS) break;
  }
#pragma unroll
  for (int off = 32; off >= 1; off >>= 1)
    firstIdx = min(firstIdx, __shfl_xor(firstIdx, off));
  for (int r = base + lane; r < NS; r += 64) o[r] = firstIdx;
}

// ---------------------------------------------------------------------------
// Grouping + 3-layer MLP + max over samples. One thread per (query, sample).
// Weights read with wave-uniform indices -> scalar loads.
// ---------------------------------------------------------------------------
template <int NS, int C1, int C2, int C3>
__global__ __launch_bounds__(256) void group_mlp_kernel(
    const float* __restrict__ xyz, const float* __restrict__ feat,
    const float* __restrict__ new_xyz, const int* __restrict__ idx,
    const float* __restrict__ w0, const float* __restrict__ b0,
    const float* __restrict__ w1, const float* __restrict__ b1,
    const float* __restrict__ w2, const float* __restrict__ b2,
    float* __restrict__ pf, int chOff)
{
  constexpr int QPB = 256 / NS;
  const int q = blockIdx.x * QPB + (int)(threadIdx.x / NS);
  const int k = (int)(threadIdx.x % NS);
  const int b = q >> 12;
  const int s = q & (SS - 1);
  const float* X = xyz + (size_t)b * NN * 3;
  const float* F = feat + (size_t)b * 6 * NN;
  const int p = idx[(size_t)q * NS + k];

  float in[9];
  in[0] = X[p * 3 + 0] - new_xyz[q * 3 + 0];
  in[1] = X[p * 3 + 1] - new_xyz[q * 3 + 1];
  in[2] = X[p * 3 + 2] - new_xyz[q * 3 + 2];
#pragma unroll
  for (int c = 0; c < 6; ++c) in[3 + c] = F[c * NN + p];

  float h1[C1];
#pragma unroll
  for (int oc = 0; oc < C1; ++oc) {
    float a = b0[oc];
#pragma unroll
    for (int c = 0; c < 9; ++c) a = fmaf(w0[oc * 9 + c], in[c], a);
    h1[oc] = fmaxf(a, 0.f);
  }
  float h2[C2];
#pragma unroll
  for (int oc = 0; oc < C2; ++oc) {
    float a = b1[oc];
#pragma unroll
    for (int c = 0; c < C1; ++c) a = fmaf(w1[oc * C1 + c], h1[c], a);
    h2[oc] = fmaxf(a, 0.f);
  }
  // third layer: compute one output channel at a time, reduce immediately
#pragma unroll
  for (int oc = 0; oc < C3; ++oc) {
    float a = b2[oc];
#pragma unroll
    for (int c = 0; c < C2; ++c) a = fmaf(w2[oc * C2 + c], h2[c], a);
    float v = fmaxf(a, 0.f);
#pragma unroll
    for (int off = NS / 2; off >= 1; off >>= 1)
      v = fmaxf(v, __shfl_xor(v, off));
    if (k == 0) pf[(((size_t)b * 96) + chOff + oc) * SS + s] = v;
  }
}

// ---------------------------------------------------------------------------
// Image branch + attention + fusion, 32-column LDS tiles.
// ---------------------------------------------------------------------------
__global__ __launch_bounds__(256) void img_fuse_kernel(
    const float* __restrict__ imgf, const float* __restrict__ pf,
    const float* __restrict__ w_img, const float* __restrict__ b_img,
    const float* __restrict__ w_fc2, const float* __restrict__ b_fc2,
    const float* __restrict__ w_fc3, const float* __restrict__ b_fc3,
    const float* __restrict__ w_pc, const float* __restrict__ b_pc,
    const float* __restrict__ w_fuse, const float* __restrict__ b_fuse,
    float* __restrict__ out)
{
  constexpr int TS = 32;
  __shared__ float x_lds[64][TS];
  __shared__ float img_lds[96][TS];
  __shared__ float ri_lds[24][TS];
  __shared__ float att_lds[TS];
  __shared__ float imgn_lds[96][TS];
  __shared__ float pf_lds[96][TS];

  const int blk = blockIdx.x;            // B * (SS/TS) = 256 blocks
  const int b = blk / (SS / TS);
  const int s0 = (blk % (SS / TS)) * TS;
  const int tid = threadIdx.x;

  for (int i = tid; i < 64 * TS; i += 256) {
    int c = i / TS, s = i % TS;
    x_lds[c][s] = imgf[((size_t)b * 64 + c) * SS + s0 + s];
  }
  for (int i = tid; i < 96 * TS; i += 256) {
    int c = i / TS, s = i % TS;
    pf_lds[c][s] = pf[((size_t)b * 96 + c) * SS + s0 + s];
  }
  __syncthreads();

  // img = relu(w_img @ x + b)
  for (int i = tid; i < 96 * TS; i += 256) {
    int oc = i / TS, s = i % TS;
    float a = b_img[oc];
#pragma unroll
    for (int c = 0; c < 64; ++c) a = fmaf(w_img[oc * 64 + c], x_lds[c][s], a);
    img_lds[oc][s] = fmaxf(a, 0.f);
  }
  __syncthreads();

  // ri = tanh(img^T @ w_fc2^T + b)
  for (int i = tid; i < 24 * TS; i += 256) {
    int r = i / TS, s = i % TS;
    float a = b_fc2[r];
#pragma unroll
    for (int c = 0; c < 96; ++c) a = fmaf(w_fc2[r * 96 + c], img_lds[c][s], a);
    ri_lds[r][s] = tanhf(a);
  }
  __syncthreads();

  if (tid < TS) {
    float a = b_fc3[0];
#pragma unroll
    for (int r = 0; r < 24; ++r) a = fmaf(w_fc3[r], ri_lds[r][tid], a);
    att_lds[tid] = 1.f / (1.f + expf(-a));
  }
  __syncthreads();

  // img_r = img + img*att (in place)
  for (int i = tid; i < 96 * TS; i += 256) {
    int c = i / TS, s = i % TS;
    float v = img_lds[c][s];
    img_lds[c][s] = fmaf(v, att_lds[s], v);
  }
  __syncthreads();

  // img_new = relu(w_pc @ img_r + b)
  for (int i = tid; i < 96 * TS; i += 256) {
    int oc = i / TS, s = i % TS;
    float a = b_pc[oc];
#pragma unroll
    for (int c = 0; c < 96; ++c) a = fmaf(w_pc[oc * 96 + c], img_lds[c][s], a);
    imgn_lds[oc][s] = fmaxf(a, 0.f);
  }
  __syncthreads();

  // out = relu(w_fuse @ [pf ; img_new] + b)
  for (int i = tid; i < 128 * TS; i += 256) {
    int oc = i / TS, s = i % TS;
    float a = b_fuse[oc];
#pragma unroll
    for (int c = 0; c < 96; ++c) a = fmaf(w_fuse[oc * 192 + c], pf_lds[c][s], a);
#pragma unroll
    for (int c = 0; c < 96; ++c) a = fmaf(w_fuse[oc * 192 + 96 + c], imgn_lds[c][s], a);
    out[((size_t)b * 128 + oc) * SS + s0 + s] = fmaxf(a, 0.f);
  }
}

// ---------------------------------------------------------------------------
extern "C" void kernel_launch(void* const* d_in, const int* in_sizes, int n_in,
                              void* d_out, int out_size, void* d_ws, size_t ws_size,
                              hipStream_t stream)
{
  const float* xyz    = (const float*)d_in[0];
  const float* feat   = (const float*)d_in[1];
  const float* imgf   = (const float*)d_in[2];
  const float* w0_0   = (const float*)d_in[3];
  const float* b0_0   = (const float*)d_in[4];
  const float* w0_1   = (const float*)d_in[5];
  const float* b0_1   = (const float*)d_in[6];
  const float* w0_2   = (const float*)d_in[7];
  const float* b0_2   = (const float*)d_in[8];
  const float* w1_0   = (const float*)d_in[9];
  const float* b1_0   = (const float*)d_in[10];
  const float* w1_1   = (const float*)d_in[11];
  const float* b1_1   = (const float*)d_in[12];
  const float* w1_2   = (const float*)d_in[13];
  const float* b1_2   = (const float*)d_in[14];
  const float* w_img  = (const float*)d_in[15];
  const float* b_img  = (const float*)d_in[16];
  const float* w_fc2  = (const float*)d_in[17];
  const float* b_fc2  = (const float*)d_in[18];
  const float* w_fc3  = (const float*)d_in[19];
  const float* b_fc3  = (const float*)d_in[20];
  const float* w_pc   = (const float*)d_in[21];
  const float* b_pc   = (const float*)d_in[22];
  const float* w_fuse = (const float*)d_in[23];
  const float* b_fuse = (const float*)d_in[24];
  float* out = (float*)d_out;

  float* nxyz = (float*)d_ws;                          // B*S*3 f32
  int*   fidx = (int*)(nxyz + (size_t)BB * SS * 3);    // B*S i32
  int*   idx0 = fidx + (size_t)BB * SS;                // B*S*16 i32
  int*   idx1 = idx0 + (size_t)BB * SS * 16;           // B*S*32 i32
  float* pf   = (float*)(idx1 + (size_t)BB * SS * 32); // B*96*S f32

  fps_kernel<<<BB, 1024, 0, stream>>>(xyz, fidx, nxyz);
  ballq_kernel<16><<<BB * SS / 4, 256, 0, stream>>>(xyz, nxyz, idx0, 0.25f);
  ballq_kernel<32><<<BB * SS / 4, 256, 0, stream>>>(xyz, nxyz, idx1, 1.0f);
  group_mlp_kernel<16, 16, 16, 32><<<BB * SS / 16, 256, 0, stream>>>(
      xyz, feat, nxyz, idx0, w0_0, b0_0, w0_1, b0_1, w0_2, b0_2, pf, 0);
  group_mlp_kernel<32, 32, 32, 64><<<BB * SS / 8, 256, 0, stream>>>(
      xyz, feat, nxyz, idx1, w1_0, b1_0, w1_1, b1_1, w1_2, b1_2, pf, 32);
  img_fuse_kernel<<<BB * SS / 32, 256, 0, stream>>>(
      imgf, pf, w_img, b_img, w_fc2, b_fc2, w_fc3, b_fc3, w_pc, b_pc,
      w_fuse, b_fuse, out);
}

// Round 2
// 9408.257 us; speedup vs baseline: 1.0623x; 1.0623x over previous
//
#include <hip/hip_runtime.h>
#include <cstdint>

static constexpr int BB = 2;
static constexpr int NN = 16384;
static constexpr int SS = 4096;

// ---------------------------------------------------------------------------
// FPS: one block per batch. 1024 threads, 16 consecutive points/thread in
// registers. Bit-exact distance math (no FMA contraction) to match the numpy
// reference, argmax with first-index tie-break.
// One barrier per iteration (double-buffered partials); winner coords are
// re-read from global xyz (L2-resident) instead of an LDS publish+barrier;
// new_xyz stores are deferred one iteration so their vmcnt drain overlaps
// the compute phase instead of stalling the barrier.
// ---------------------------------------------------------------------------
__global__ __launch_bounds__(1024) void fps_kernel(
    const float* __restrict__ xyz, float* __restrict__ new_xyz)
{
  const int b = blockIdx.x;
  const float* X = xyz + (size_t)b * NN * 3;
  float* NX = new_xyz + (size_t)b * SS * 3;
  const int t = threadIdx.x;
  constexpr int PPT = NN / 1024;  // 16

  float px[PPT], py[PPT], pz[PPT], dist[PPT];
#pragma unroll
  for (int i = 0; i < PPT; ++i) {
    int p = t * PPT + i;
    px[i] = X[p * 3 + 0];
    py[i] = X[p * 3 + 1];
    pz[i] = X[p * 3 + 2];
    dist[i] = 1e10f;
  }

  __shared__ float s_wval[2][16];
  __shared__ int   s_widx[2][16];

  const int lane = t & 63;
  const int wid = t >> 6;

  int sel = 0;  // selection of iteration it-1 (iteration 0 selects point 0)
  for (int it = 1; it < SS; ++it) {
    // coords of previous selection: wave-uniform global load (L2-resident)
    const float sx = X[sel * 3 + 0];
    const float sy = X[sel * 3 + 1];
    const float sz = X[sel * 3 + 2];
    // deferred store of previous selection's coords; drains during compute
    if (t == 0) {
      NX[(it - 1) * 3 + 0] = sx;
      NX[(it - 1) * 3 + 1] = sy;
      NX[(it - 1) * 3 + 2] = sz;
    }

    float bval = -1.f;
    int bidx = 0;
#pragma unroll
    for (int i = 0; i < PPT; ++i) {
      float dx = __fsub_rn(px[i], sx);
      float dy = __fsub_rn(py[i], sy);
      float dz = __fsub_rn(pz[i], sz);
      float d = __fadd_rn(__fadd_rn(__fmul_rn(dx, dx), __fmul_rn(dy, dy)),
                          __fmul_rn(dz, dz));
      float nd = fminf(dist[i], d);
      dist[i] = nd;
      if (nd > bval) { bval = nd; bidx = t * PPT + i; }  // ascending i -> min idx on ties
    }
    // wave-level argmax reduce, tie -> smaller index
#pragma unroll
    for (int off = 32; off >= 1; off >>= 1) {
      float ov = __shfl_xor(bval, off);
      int   oi = __shfl_xor(bidx, off);
      if (ov > bval || (ov == bval && oi < bidx)) { bval = ov; bidx = oi; }
    }
    const int pb = it & 1;
    if (lane == 0) { s_wval[pb][wid] = bval; s_widx[pb][wid] = bidx; }
    __syncthreads();
    // every wave redundantly reduces the 16 wave-partials (no broadcast needed)
    float rv = s_wval[pb][lane & 15];
    int   ri = s_widx[pb][lane & 15];
#pragma unroll
    for (int off = 8; off >= 1; off >>= 1) {
      float ov = __shfl_xor(rv, off);
      int   oi = __shfl_xor(ri, off);
      if (ov > rv || (ov == rv && oi < ri)) { rv = ov; ri = oi; }
    }
    sel = ri;  // identical in all lanes/waves
  }
  if (t == 0) {
    NX[(SS - 1) * 3 + 0] = X[sel * 3 + 0];
    NX[(SS - 1) * 3 + 1] = X[sel * 3 + 1];
    NX[(SS - 1) * 3 + 2] = X[sel * 3 + 2];
  }
}

// ---------------------------------------------------------------------------
// Ball query: one 64-lane wave per query point. Emits the first NS in-radius
// point indices in ascending order (matches reference top_k(-keys) trick),
// pads with the first hit.
// ---------------------------------------------------------------------------
template <int NS>
__global__ __launch_bounds__(256) void ballq_kernel(
    const float* __restrict__ xyz, const float* __restrict__ new_xyz,
    int* __restrict__ out, float r2)
{
  const int q = blockIdx.x * 4 + (threadIdx.x >> 6);
  const int lane = threadIdx.x & 63;
  const int b = q >> 12;  // q / SS
  const float* X = xyz + (size_t)b * NN * 3;
  const float cx = new_xyz[q * 3 + 0];
  const float cy = new_xyz[q * 3 + 1];
  const float cz = new_xyz[q * 3 + 2];
  int* o = out + (size_t)q * NS;
  int base = 0;
  int firstIdx = 0x7fffffff;
  for (int c0 = 0; c0 < NN; c0 += 64) {
    const int p = c0 + lane;
    float dx = __fsub_rn(cx, X[p * 3 + 0]);
    float dy = __fsub_rn(cy, X[p * 3 + 1]);
    float dz = __fsub_rn(cz, X[p * 3 + 2]);
    float d2 = __fadd_rn(__fadd_rn(__fmul_rn(dx, dx), __fmul_rn(dy, dy)),
                         __fmul_rn(dz, dz));
    const bool inb = d2 < r2;
    const unsigned long long m = __ballot(inb);
    if (inb) {
      int rank = base + (int)__popcll(m & ((1ull << lane) - 1ull));
      if (rank < NS) {
        o[rank] = p;
        if (rank == 0) firstIdx = p;
      }
    }
    base += (int)__popcll(m);
    if (base >= NS) break;
  }
#pragma unroll
  for (int off = 32; off >= 1; off >>= 1)
    firstIdx = min(firstIdx, __shfl_xor(firstIdx, off));
  for (int r = base + lane; r < NS; r += 64) o[r] = firstIdx;
}

// ---------------------------------------------------------------------------
// Grouping + 3-layer MLP + max over samples. One thread per (query, sample).
// Weights read with wave-uniform indices -> scalar loads.
// ---------------------------------------------------------------------------
template <int NS, int C1, int C2, int C3>
__global__ __launch_bounds__(256) void group_mlp_kernel(
    const float* __restrict__ xyz, const float* __restrict__ feat,
    const float* __restrict__ new_xyz, const int* __restrict__ idx,
    const float* __restrict__ w0, const float* __restrict__ b0,
    const float* __restrict__ w1, const float* __restrict__ b1,
    const float* __restrict__ w2, const float* __restrict__ b2,
    float* __restrict__ pf, int chOff)
{
  constexpr int QPB = 256 / NS;
  const int q = blockIdx.x * QPB + (int)(threadIdx.x / NS);
  const int k = (int)(threadIdx.x % NS);
  const int b = q >> 12;
  const int s = q & (SS - 1);
  const float* X = xyz + (size_t)b * NN * 3;
  const float* F = feat + (size_t)b * 6 * NN;
  const int p = idx[(size_t)q * NS + k];

  float in[9];
  in[0] = X[p * 3 + 0] - new_xyz[q * 3 + 0];
  in[1] = X[p * 3 + 1] - new_xyz[q * 3 + 1];
  in[2] = X[p * 3 + 2] - new_xyz[q * 3 + 2];
#pragma unroll
  for (int c = 0; c < 6; ++c) in[3 + c] = F[c * NN + p];

  float h1[C1];
#pragma unroll
  for (int oc = 0; oc < C1; ++oc) {
    float a = b0[oc];
#pragma unroll
    for (int c = 0; c < 9; ++c) a = fmaf(w0[oc * 9 + c], in[c], a);
    h1[oc] = fmaxf(a, 0.f);
  }
  float h2[C2];
#pragma unroll
  for (int oc = 0; oc < C2; ++oc) {
    float a = b1[oc];
#pragma unroll
    for (int c = 0; c < C1; ++c) a = fmaf(w1[oc * C1 + c], h1[c], a);
    h2[oc] = fmaxf(a, 0.f);
  }
  // third layer: compute one output channel at a time, reduce immediately
#pragma unroll
  for (int oc = 0; oc < C3; ++oc) {
    float a = b2[oc];
#pragma unroll
    for (int c = 0; c < C2; ++c) a = fmaf(w2[oc * C2 + c], h2[c], a);
    float v = fmaxf(a, 0.f);
#pragma unroll
    for (int off = NS / 2; off >= 1; off >>= 1)
      v = fmaxf(v, __shfl_xor(v, off));
    if (k == 0) pf[(((size_t)b * 96) + chOff + oc) * SS + s] = v;
  }
}

// ---------------------------------------------------------------------------
// Image branch + attention + fusion, 32-column LDS tiles.
// ---------------------------------------------------------------------------
__global__ __launch_bounds__(256) void img_fuse_kernel(
    const float* __restrict__ imgf, const float* __restrict__ pf,
    const float* __restrict__ w_img, const float* __restrict__ b_img,
    const float* __restrict__ w_fc2, const float* __restrict__ b_fc2,
    const float* __restrict__ w_fc3, const float* __restrict__ b_fc3,
    const float* __restrict__ w_pc, const float* __restrict__ b_pc,
    const float* __restrict__ w_fuse, const float* __restrict__ b_fuse,
    float* __restrict__ out)
{
  constexpr int TS = 32;
  __shared__ float x_lds[64][TS];
  __shared__ float img_lds[96][TS];
  __shared__ float ri_lds[24][TS];
  __shared__ float att_lds[TS];
  __shared__ float imgn_lds[96][TS];
  __shared__ float pf_lds[96][TS];

  const int blk = blockIdx.x;            // B * (SS/TS) = 256 blocks
  const int b = blk / (SS / TS);
  const int s0 = (blk % (SS / TS)) * TS;
  const int tid = threadIdx.x;

  for (int i = tid; i < 64 * TS; i += 256) {
    int c = i / TS, s = i % TS;
    x_lds[c][s] = imgf[((size_t)b * 64 + c) * SS + s0 + s];
  }
  for (int i = tid; i < 96 * TS; i += 256) {
    int c = i / TS, s = i % TS;
    pf_lds[c][s] = pf[((size_t)b * 96 + c) * SS + s0 + s];
  }
  __syncthreads();

  // img = relu(w_img @ x + b)
  for (int i = tid; i < 96 * TS; i += 256) {
    int oc = i / TS, s = i % TS;
    float a = b_img[oc];
#pragma unroll
    for (int c = 0; c < 64; ++c) a = fmaf(w_img[oc * 64 + c], x_lds[c][s], a);
    img_lds[oc][s] = fmaxf(a, 0.f);
  }
  __syncthreads();

  // ri = tanh(img^T @ w_fc2^T + b)
  for (int i = tid; i < 24 * TS; i += 256) {
    int r = i / TS, s = i % TS;
    float a = b_fc2[r];
#pragma unroll
    for (int c = 0; c < 96; ++c) a = fmaf(w_fc2[r * 96 + c], img_lds[c][s], a);
    ri_lds[r][s] = tanhf(a);
  }
  __syncthreads();

  if (tid < TS) {
    float a = b_fc3[0];
#pragma unroll
    for (int r = 0; r < 24; ++r) a = fmaf(w_fc3[r], ri_lds[r][tid], a);
    att_lds[tid] = 1.f / (1.f + expf(-a));
  }
  __syncthreads();

  // img_r = img + img*att (in place)
  for (int i = tid; i < 96 * TS; i += 256) {
    int c = i / TS, s = i % TS;
    float v = img_lds[c][s];
    img_lds[c][s] = fmaf(v, att_lds[s], v);
  }
  __syncthreads();

  // img_new = relu(w_pc @ img_r + b)
  for (int i = tid; i < 96 * TS; i += 256) {
    int oc = i / TS, s = i % TS;
    float a = b_pc[oc];
#pragma unroll
    for (int c = 0; c < 96; ++c) a = fmaf(w_pc[oc * 96 + c], img_lds[c][s], a);
    imgn_lds[oc][s] = fmaxf(a, 0.f);
  }
  __syncthreads();

  // out = relu(w_fuse @ [pf ; img_new] + b)
  for (int i = tid; i < 128 * TS; i += 256) {
    int oc = i / TS, s = i % TS;
    float a = b_fuse[oc];
#pragma unroll
    for (int c = 0; c < 96; ++c) a = fmaf(w_fuse[oc * 192 + c], pf_lds[c][s], a);
#pragma unroll
    for (int c = 0; c < 96; ++c) a = fmaf(w_fuse[oc * 192 + 96 + c], imgn_lds[c][s], a);
    out[((size_t)b * 128 + oc) * SS + s0 + s] = fmaxf(a, 0.f);
  }
}

// ---------------------------------------------------------------------------
extern "C" void kernel_launch(void* const* d_in, const int* in_sizes, int n_in,
                              void* d_out, int out_size, void* d_ws, size_t ws_size,
                              hipStream_t stream)
{
  const float* xyz    = (const float*)d_in[0];
  const float* feat   = (const float*)d_in[1];
  const float* imgf   = (const float*)d_in[2];
  const float* w0_0   = (const float*)d_in[3];
  const float* b0_0   = (const float*)d_in[4];
  const float* w0_1   = (const float*)d_in[5];
  const float* b0_1   = (const float*)d_in[6];
  const float* w0_2   = (const float*)d_in[7];
  const float* b0_2   = (const float*)d_in[8];
  const float* w1_0   = (const float*)d_in[9];
  const float* b1_0   = (const float*)d_in[10];
  const float* w1_1   = (const float*)d_in[11];
  const float* b1_1   = (const float*)d_in[12];
  const float* w1_2   = (const float*)d_in[13];
  const float* b1_2   = (const float*)d_in[14];
  const float* w_img  = (const float*)d_in[15];
  const float* b_img  = (const float*)d_in[16];
  const float* w_fc2  = (const float*)d_in[17];
  const float* b_fc2  = (const float*)d_in[18];
  const float* w_fc3  = (const float*)d_in[19];
  const float* b_fc3  = (const float*)d_in[20];
  const float* w_pc   = (const float*)d_in[21];
  const float* b_pc   = (const float*)d_in[22];
  const float* w_fuse = (const float*)d_in[23];
  const float* b_fuse = (const float*)d_in[24];
  float* out = (float*)d_out;

  float* nxyz = (float*)d_ws;                          // B*S*3 f32
  int*   idx0 = (int*)(nxyz + (size_t)BB * SS * 3);    // B*S*16 i32
  int*   idx1 = idx0 + (size_t)BB * SS * 16;           // B*S*32 i32
  float* pf   = (float*)(idx1 + (size_t)BB * SS * 32); // B*96*S f32

  fps_kernel<<<BB, 1024, 0, stream>>>(xyz, nxyz);
  ballq_kernel<16><<<BB * SS / 4, 256, 0, stream>>>(xyz, nxyz, idx0, 0.25f);
  ballq_kernel<32><<<BB * SS / 4, 256, 0, stream>>>(xyz, nxyz, idx1, 1.0f);
  group_mlp_kernel<16, 16, 16, 32><<<BB * SS / 16, 256, 0, stream>>>(
      xyz, feat, nxyz, idx0, w0_0, b0_0, w0_1, b0_1, w0_2, b0_2, pf, 0);
  group_mlp_kernel<32, 32, 32, 64><<<BB * SS / 8, 256, 0, stream>>>(
      xyz, feat, nxyz, idx1, w1_0, b1_0, w1_1, b1_1, w1_2, b1_2, pf, 32);
  img_fuse_kernel<<<BB * SS / 32, 256, 0, stream>>>(
      imgf, pf, w_img, b_img, w_fc2, b_fc2, w_fc3, b_fc3, w_pc, b_pc,
      w_fuse, b_fuse, out);
}

// Round 3
// 6459.845 us; speedup vs baseline: 1.5472x; 1.4564x over previous
//
#include <hip/hip_runtime.h>
#include <cstdint>

typedef unsigned long long u64;

static constexpr int BB = 2;
static constexpr int NN = 16384;
static constexpr int SS = 4096;

// one step of a u64 max-combine via DPP (CTRL is a DPP control immediate)
template <int CTRL>
__device__ __forceinline__ u64 dpp_max_step(u64 k) {
  int lo = (int)(unsigned)(k & 0xffffffffull);
  int hi = (int)(unsigned)(k >> 32);
  int slo = __builtin_amdgcn_update_dpp(0, lo, CTRL, 0xF, 0xF, true);
  int shi = __builtin_amdgcn_update_dpp(0, hi, CTRL, 0xF, 0xF, true);
  u64 o = ((u64)(unsigned)shi << 32) | (u64)(unsigned)slo;
  return (o > k) ? o : k;
}

// ---------------------------------------------------------------------------
// FPS: one block per batch, 1024 threads, 16 consecutive points/thread held in
// NAMED scalar registers (arrays were being demoted to scratch: R1/R2 showed
// VGPR_Count 48 < 64 live floats and 200-780 MB FETCH_SIZE -> spill traffic).
// Bit-exact distance math (separate mul/add, no FMA) to match numpy; argmax
// tie-break = lowest original index via packed key (dist_bits<<32)|~idx.
// Reduction: DPP wave argmax (row_shr 1,2,4,8 + row_bcast15/31, result lane 63)
// -> 16 partials in LDS -> one barrier -> DPP row_ror 8,4,2,1 over partials.
// ---------------------------------------------------------------------------
__global__ __launch_bounds__(1024) void fps_kernel(
    const float* __restrict__ xyz, float* __restrict__ new_xyz)
{
  const int b = blockIdx.x;
  const float* X = xyz + (size_t)b * NN * 3;
  float* NX = new_xyz + (size_t)b * SS * 3;
  const int t = threadIdx.x;
  const int lane = t & 63;
  const int wid = t >> 6;
  const int base = t * 16;

  // 16 consecutive points = 192 B = 12 float4 loads, unpacked to named scalars
  const float4* P4 = (const float4*)(X + (size_t)t * 48);
  float4 g0 = P4[0], g1 = P4[1], g2 = P4[2], g3 = P4[3], g4 = P4[4], g5 = P4[5],
         g6 = P4[6], g7 = P4[7], g8 = P4[8], g9 = P4[9], g10 = P4[10], g11 = P4[11];
  float px0 = g0.x,  py0 = g0.y,  pz0 = g0.z;
  float px1 = g0.w,  py1 = g1.x,  pz1 = g1.y;
  float px2 = g1.z,  py2 = g1.w,  pz2 = g2.x;
  float px3 = g2.y,  py3 = g2.z,  pz3 = g2.w;
  float px4 = g3.x,  py4 = g3.y,  pz4 = g3.z;
  float px5 = g3.w,  py5 = g4.x,  pz5 = g4.y;
  float px6 = g4.z,  py6 = g4.w,  pz6 = g5.x;
  float px7 = g5.y,  py7 = g5.z,  pz7 = g5.w;
  float px8 = g6.x,  py8 = g6.y,  pz8 = g6.z;
  float px9 = g6.w,  py9 = g7.x,  pz9 = g7.y;
  float px10 = g7.z, py10 = g7.w, pz10 = g8.x;
  float px11 = g8.y, py11 = g8.z, pz11 = g8.w;
  float px12 = g9.x, py12 = g9.y, pz12 = g9.z;
  float px13 = g9.w, py13 = g10.x, pz13 = g10.y;
  float px14 = g10.z, py14 = g10.w, pz14 = g11.x;
  float px15 = g11.y, py15 = g11.z, pz15 = g11.w;

  float d0 = 1e10f, d1 = 1e10f, d2 = 1e10f, d3 = 1e10f,
        d4 = 1e10f, d5 = 1e10f, d6 = 1e10f, d7 = 1e10f,
        d8 = 1e10f, d9 = 1e10f, d10 = 1e10f, d11 = 1e10f,
        d12 = 1e10f, d13 = 1e10f, d14 = 1e10f, d15 = 1e10f;

  __shared__ u64 s_part[2][16];

  int sel = 0;  // selection of previous iteration (iteration 0 selects point 0)
  for (int it = 1; it < SS; ++it) {
    // winner coords: scalar (wave-uniform) load, L2-resident
    const float sx = X[sel * 3 + 0];
    const float sy = X[sel * 3 + 1];
    const float sz = X[sel * 3 + 2];
    // deferred store of previous selection; drains under the update phase
    if (t == 0) {
      NX[(it - 1) * 3 + 0] = sx;
      NX[(it - 1) * 3 + 1] = sy;
      NX[(it - 1) * 3 + 2] = sz;
    }

    float bval = -1.f;
    int bidx = 0;
#define UPD(dd, ax, ay, az, ii)                                              \
    {                                                                        \
      float dx = __fsub_rn(ax, sx);                                          \
      float dy = __fsub_rn(ay, sy);                                          \
      float dz = __fsub_rn(az, sz);                                          \
      float dsq = __fadd_rn(__fadd_rn(__fmul_rn(dx, dx), __fmul_rn(dy, dy)), \
                            __fmul_rn(dz, dz));                              \
      dd = fminf(dd, dsq);                                                   \
      if (dd > bval) { bval = dd; bidx = base + ii; }                        \
    }
    UPD(d0,  px0,  py0,  pz0,  0)
    UPD(d1,  px1,  py1,  pz1,  1)
    UPD(d2,  px2,  py2,  pz2,  2)
    UPD(d3,  px3,  py3,  pz3,  3)
    UPD(d4,  px4,  py4,  pz4,  4)
    UPD(d5,  px5,  py5,  pz5,  5)
    UPD(d6,  px6,  py6,  pz6,  6)
    UPD(d7,  px7,  py7,  pz7,  7)
    UPD(d8,  px8,  py8,  pz8,  8)
    UPD(d9,  px9,  py9,  pz9,  9)
    UPD(d10, px10, py10, pz10, 10)
    UPD(d11, px11, py11, pz11, 11)
    UPD(d12, px12, py12, pz12, 12)
    UPD(d13, px13, py13, pz13, 13)
    UPD(d14, px14, py14, pz14, 14)
    UPD(d15, px15, py15, pz15, 15)
#undef UPD

    // packed key: max dist wins; on equal dist, ~idx max -> lowest index wins
    u64 k = ((u64)__float_as_uint(bval) << 32) | (u64)(unsigned)(~bidx);
    // wave argmax: prefix combine, full wave max lands in lane 63
    k = dpp_max_step<0x111>(k);  // row_shr:1
    k = dpp_max_step<0x112>(k);  // row_shr:2
    k = dpp_max_step<0x114>(k);  // row_shr:4
    k = dpp_max_step<0x118>(k);  // row_shr:8
    k = dpp_max_step<0x142>(k);  // row_bcast:15
    k = dpp_max_step<0x143>(k);  // row_bcast:31

    const int pb = it & 1;
    if (lane == 63) s_part[pb][wid] = k;
    __syncthreads();
    // every wave redundantly reduces the 16 partials; ror reduce -> all lanes
    u64 kk = s_part[pb][lane & 15];
    kk = dpp_max_step<0x128>(kk);  // row_ror:8
    kk = dpp_max_step<0x124>(kk);  // row_ror:4
    kk = dpp_max_step<0x122>(kk);  // row_ror:2
    kk = dpp_max_step<0x121>(kk);  // row_ror:1
    sel = (int)(~(unsigned)(kk & 0xffffffffull));
    sel = __builtin_amdgcn_readfirstlane(sel);
  }
  if (t == 0) {
    NX[(SS - 1) * 3 + 0] = X[sel * 3 + 0];
    NX[(SS - 1) * 3 + 1] = X[sel * 3 + 1];
    NX[(SS - 1) * 3 + 2] = X[sel * 3 + 2];
  }
}

// ---------------------------------------------------------------------------
// Ball query: one 64-lane wave per query point. Emits the first NS in-radius
// point indices in ascending order (matches reference top_k(-keys) trick),
// pads with the first hit.
// ---------------------------------------------------------------------------
template <int NS>
__global__ __launch_bounds__(256) void ballq_kernel(
    const float* __restrict__ xyz, const float* __restrict__ new_xyz,
    int* __restrict__ out, float r2)
{
  const int q = blockIdx.x * 4 + (threadIdx.x >> 6);
  const int lane = threadIdx.x & 63;
  const int b = q >> 12;  // q / SS
  const float* X = xyz + (size_t)b * NN * 3;
  const float cx = new_xyz[q * 3 + 0];
  const float cy = new_xyz[q * 3 + 1];
  const float cz = new_xyz[q * 3 + 2];
  int* o = out + (size_t)q * NS;
  int base = 0;
  int firstIdx = 0x7fffffff;
  for (int c0 = 0; c0 < NN; c0 += 64) {
    const int p = c0 + lane;
    float dx = __fsub_rn(cx, X[p * 3 + 0]);
    float dy = __fsub_rn(cy, X[p * 3 + 1]);
    float dz = __fsub_rn(cz, X[p * 3 + 2]);
    float d2 = __fadd_rn(__fadd_rn(__fmul_rn(dx, dx), __fmul_rn(dy, dy)),
                         __fmul_rn(dz, dz));
    const bool inb = d2 < r2;
    const unsigned long long m = __ballot(inb);
    if (inb) {
      int rank = base + (int)__popcll(m & ((1ull << lane) - 1ull));
      if (rank < NS) {
        o[rank] = p;
        if (rank == 0) firstIdx = p;
      }
    }
    base += (int)__popcll(m);
    if (base >= NS) break;
  }
#pragma unroll
  for (int off = 32; off >= 1; off >>= 1)
    firstIdx = min(firstIdx, __shfl_xor(firstIdx, off));
  for (int r = base + lane; r < NS; r += 64) o[r] = firstIdx;
}

// ---------------------------------------------------------------------------
// Grouping + 3-layer MLP + max over samples. One thread per (query, sample).
// Weights read with wave-uniform indices -> scalar loads.
// ---------------------------------------------------------------------------
template <int NS, int C1, int C2, int C3>
__global__ __launch_bounds__(256) void group_mlp_kernel(
    const float* __restrict__ xyz, const float* __restrict__ feat,
    const float* __restrict__ new_xyz, const int* __restrict__ idx,
    const float* __restrict__ w0, const float* __restrict__ b0,
    const float* __restrict__ w1, const float* __restrict__ b1,
    const float* __restrict__ w2, const float* __restrict__ b2,
    float* __restrict__ pf, int chOff)
{
  constexpr int QPB = 256 / NS;
  const int q = blockIdx.x * QPB + (int)(threadIdx.x / NS);
  const int k = (int)(threadIdx.x % NS);
  const int b = q >> 12;
  const int s = q & (SS - 1);
  const float* X = xyz + (size_t)b * NN * 3;
  const float* F = feat + (size_t)b * 6 * NN;
  const int p = idx[(size_t)q * NS + k];

  float in[9];
  in[0] = X[p * 3 + 0] - new_xyz[q * 3 + 0];
  in[1] = X[p * 3 + 1] - new_xyz[q * 3 + 1];
  in[2] = X[p * 3 + 2] - new_xyz[q * 3 + 2];
#pragma unroll
  for (int c = 0; c < 6; ++c) in[3 + c] = F[c * NN + p];

  float h1[C1];
#pragma unroll
  for (int oc = 0; oc < C1; ++oc) {
    float a = b0[oc];
#pragma unroll
    for (int c = 0; c < 9; ++c) a = fmaf(w0[oc * 9 + c], in[c], a);
    h1[oc] = fmaxf(a, 0.f);
  }
  float h2[C2];
#pragma unroll
  for (int oc = 0; oc < C2; ++oc) {
    float a = b1[oc];
#pragma unroll
    for (int c = 0; c < C1; ++c) a = fmaf(w1[oc * C1 + c], h1[c], a);
    h2[oc] = fmaxf(a, 0.f);
  }
  // third layer: compute one output channel at a time, reduce immediately
#pragma unroll
  for (int oc = 0; oc < C3; ++oc) {
    float a = b2[oc];
#pragma unroll
    for (int c = 0; c < C2; ++c) a = fmaf(w2[oc * C2 + c], h2[c], a);
    float v = fmaxf(a, 0.f);
#pragma unroll
    for (int off = NS / 2; off >= 1; off >>= 1)
      v = fmaxf(v, __shfl_xor(v, off));
    if (k == 0) pf[(((size_t)b * 96) + chOff + oc) * SS + s] = v;
  }
}

// ---------------------------------------------------------------------------
// Image branch + attention + fusion, 32-column LDS tiles.
// ---------------------------------------------------------------------------
__global__ __launch_bounds__(256) void img_fuse_kernel(
    const float* __restrict__ imgf, const float* __restrict__ pf,
    const float* __restrict__ w_img, const float* __restrict__ b_img,
    const float* __restrict__ w_fc2, const float* __restrict__ b_fc2,
    const float* __restrict__ w_fc3, const float* __restrict__ b_fc3,
    const float* __restrict__ w_pc, const float* __restrict__ b_pc,
    const float* __restrict__ w_fuse, const float* __restrict__ b_fuse,
    float* __restrict__ out)
{
  constexpr int TS = 32;
  __shared__ float x_lds[64][TS];
  __shared__ float img_lds[96][TS];
  __shared__ float ri_lds[24][TS];
  __shared__ float att_lds[TS];
  __shared__ float imgn_lds[96][TS];
  __shared__ float pf_lds[96][TS];

  const int blk = blockIdx.x;            // B * (SS/TS) = 256 blocks
  const int b = blk / (SS / TS);
  const int s0 = (blk % (SS / TS)) * TS;
  const int tid = threadIdx.x;

  for (int i = tid; i < 64 * TS; i += 256) {
    int c = i / TS, s = i % TS;
    x_lds[c][s] = imgf[((size_t)b * 64 + c) * SS + s0 + s];
  }
  for (int i = tid; i < 96 * TS; i += 256) {
    int c = i / TS, s = i % TS;
    pf_lds[c][s] = pf[((size_t)b * 96 + c) * SS + s0 + s];
  }
  __syncthreads();

  // img = relu(w_img @ x + b)
  for (int i = tid; i < 96 * TS; i += 256) {
    int oc = i / TS, s = i % TS;
    float a = b_img[oc];
#pragma unroll
    for (int c = 0; c < 64; ++c) a = fmaf(w_img[oc * 64 + c], x_lds[c][s], a);
    img_lds[oc][s] = fmaxf(a, 0.f);
  }
  __syncthreads();

  // ri = tanh(img^T @ w_fc2^T + b)
  for (int i = tid; i < 24 * TS; i += 256) {
    int r = i / TS, s = i % TS;
    float a = b_fc2[r];
#pragma unroll
    for (int c = 0; c < 96; ++c) a = fmaf(w_fc2[r * 96 + c], img_lds[c][s], a);
    ri_lds[r][s] = tanhf(a);
  }
  __syncthreads();

  if (tid < TS) {
    float a = b_fc3[0];
#pragma unroll
    for (int r = 0; r < 24; ++r) a = fmaf(w_fc3[r], ri_lds[r][tid], a);
    att_lds[tid] = 1.f / (1.f + expf(-a));
  }
  __syncthreads();

  // img_r = img + img*att (in place)
  for (int i = tid; i < 96 * TS; i += 256) {
    int c = i / TS, s = i % TS;
    float v = img_lds[c][s];
    img_lds[c][s] = fmaf(v, att_lds[s], v);
  }
  __syncthreads();

  // img_new = relu(w_pc @ img_r + b)
  for (int i = tid; i < 96 * TS; i += 256) {
    int oc = i / TS, s = i % TS;
    float a = b_pc[oc];
#pragma unroll
    for (int c = 0; c < 96; ++c) a = fmaf(w_pc[oc * 96 + c], img_lds[c][s], a);
    imgn_lds[oc][s] = fmaxf(a, 0.f);
  }
  __syncthreads();

  // out = relu(w_fuse @ [pf ; img_new] + b)
  for (int i = tid; i < 128 * TS; i += 256) {
    int oc = i / TS, s = i % TS;
    float a = b_fuse[oc];
#pragma unroll
    for (int c = 0; c < 96; ++c) a = fmaf(w_fuse[oc * 192 + c], pf_lds[c][s], a);
#pragma unroll
    for (int c = 0; c < 96; ++c) a = fmaf(w_fuse[oc * 192 + 96 + c], imgn_lds[c][s], a);
    out[((size_t)b * 128 + oc) * SS + s0 + s] = fmaxf(a, 0.f);
  }
}

// ---------------------------------------------------------------------------
extern "C" void kernel_launch(void* const* d_in, const int* in_sizes, int n_in,
                              void* d_out, int out_size, void* d_ws, size_t ws_size,
                              hipStream_t stream)
{
  const float* xyz    = (const float*)d_in[0];
  const float* feat   = (const float*)d_in[1];
  const float* imgf   = (const float*)d_in[2];
  const float* w0_0   = (const float*)d_in[3];
  const float* b0_0   = (const float*)d_in[4];
  const float* w0_1   = (const float*)d_in[5];
  const float* b0_1   = (const float*)d_in[6];
  const float* w0_2   = (const float*)d_in[7];
  const float* b0_2   = (const float*)d_in[8];
  const float* w1_0   = (const float*)d_in[9];
  const float* b1_0   = (const float*)d_in[10];
  const float* w1_1   = (const float*)d_in[11];
  const float* b1_1   = (const float*)d_in[12];
  const float* w1_2   = (const float*)d_in[13];
  const float* b1_2   = (const float*)d_in[14];
  const float* w_img  = (const float*)d_in[15];
  const float* b_img  = (const float*)d_in[16];
  const float* w_fc2  = (const float*)d_in[17];
  const float* b_fc2  = (const float*)d_in[18];
  const float* w_fc3  = (const float*)d_in[19];
  const float* b_fc3  = (const float*)d_in[20];
  const float* w_pc   = (const float*)d_in[21];
  const float* b_pc   = (const float*)d_in[22];
  const float* w_fuse = (const float*)d_in[23];
  const float* b_fuse = (const float*)d_in[24];
  float* out = (float*)d_out;

  float* nxyz = (float*)d_ws;                          // B*S*3 f32
  int*   idx0 = (int*)(nxyz + (size_t)BB * SS * 3);    // B*S*16 i32
  int*   idx1 = idx0 + (size_t)BB * SS * 16;           // B*S*32 i32
  float* pf   = (float*)(idx1 + (size_t)BB * SS * 32); // B*96*S f32

  fps_kernel<<<BB, 1024, 0, stream>>>(xyz, nxyz);
  ballq_kernel<16><<<BB * SS / 4, 256, 0, stream>>>(xyz, nxyz, idx0, 0.25f);
  ballq_kernel<32><<<BB * SS / 4, 256, 0, stream>>>(xyz, nxyz, idx1, 1.0f);
  group_mlp_kernel<16, 16, 16, 32><<<BB * SS / 16, 256, 0, stream>>>(
      xyz, feat, nxyz, idx0, w0_0, b0_0, w0_1, b0_1, w0_2, b0_2, pf, 0);
  group_mlp_kernel<32, 32, 32, 64><<<BB * SS / 8, 256, 0, stream>>>(
      xyz, feat, nxyz, idx1, w1_0, b1_0, w1_1, b1_1, w1_2, b1_2, pf, 32);
  img_fuse_kernel<<<BB * SS / 32, 256, 0, stream>>>(
      imgf, pf, w_img, b_img, w_fc2, b_fc2, w_fc3, b_fc3, w_pc, b_pc,
      w_fuse, b_fuse, out);
}